// Round 7
// baseline (655.193 us; speedup 1.0000x reference)
//
#include <hip/hip_runtime.h>

#define NEG 0.2f
typedef unsigned short u16;
typedef __bf16 bf8 __attribute__((ext_vector_type(8)));
typedef float f4 __attribute__((ext_vector_type(4)));
typedef u16 u16x8 __attribute__((ext_vector_type(8)));
typedef u16 u16x4 __attribute__((ext_vector_type(4)));

// ---- workspace layout (in floats) ----
#define OFF_PREM  0ull                        // f32 [25000][128] msg-part of pre
#define SZ_PREM   (25000ull*128ull)
#define OFF_P16   (OFF_PREM + SZ_PREM)        // u16 [25000][512]: [0:256)=ni, [256:512)=nj (bf16)
#define SZ_P16    (25000ull*256ull)
#define OFF_BCAT  (OFF_P16 + SZ_P16)
#define SZ_BCAT   (128ull*640ull)
#define OFF_BTOT  (OFF_BCAT + SZ_BCAT)
#define SZ_BTOT   256ull
#define OFF_AGG   (OFF_BTOT + SZ_BTOT)
#define SZ_AGG    (25000ull*128ull)
#define OFF_CNT   (OFF_AGG + SZ_AGG)          // (zeroed)
#define SZ_CNT    25000ull
#define OFF_CUR   (OFF_CNT + SZ_CNT)
#define SZ_CUR    25000ull
#define OFF_RST   (OFF_CUR + SZ_CUR)          // row start (preserved)
#define SZ_RST    25000ull
#define OFF_PERM  (OFF_RST + SZ_RST)
#define SZ_PERM   400000ull
#define OFF_SRC   (OFF_PERM + SZ_PERM)        // src per sorted pos
#define SZ_SRC    400000ull
#define OFF_EWF   (OFF_SRC + SZ_SRC)          // u16[16384] MFMA-frag-packed e_W
#define SZ_EWF    8192ull
#define OFF_MWF   (OFF_EWF + SZ_EWF)          // u16[8192] MFMA-frag-packed msg_W edge half
#define SZ_MWF    4096ull

// f32 -> bf16 bits, round-to-nearest-even
__device__ __forceinline__ u16 f2b(float f) {
    unsigned u = __float_as_uint(f);
    return (u16)((u + 0x7FFFu + ((u >> 16) & 1u)) >> 16);
}
__device__ __forceinline__ float b2f(u16 v) {
    return __uint_as_float(((unsigned)v) << 16);
}
__device__ __forceinline__ bf8 pack8(float4 a, float4 b) {
    union { u16 u[8]; bf8 v; } x;
    x.u[0] = f2b(a.x); x.u[1] = f2b(a.y); x.u[2] = f2b(a.z); x.u[3] = f2b(a.w);
    x.u[4] = f2b(b.x); x.u[5] = f2b(b.y); x.u[6] = f2b(b.z); x.u[7] = f2b(b.w);
    return x.v;
}

// ---- K0: concat weights; total bias; MFMA frag packing ----
__global__ void k_prep(const float* __restrict__ niW, const float* __restrict__ njW,
                       const float* __restrict__ msgW, const float* __restrict__ eW,
                       const float* __restrict__ nib, const float* __restrict__ njb,
                       const float* __restrict__ eb,
                       float* __restrict__ bcat, float* __restrict__ btot,
                       u16* __restrict__ ewfrag, u16* __restrict__ msgfrag) {
    int idx = blockIdx.x * 256 + threadIdx.x;
    if (idx < 128 * 640) {
        int k = idx / 640, c = idx % 640;
        float v = (c < 256) ? niW[k * 256 + c]
                : (c < 512) ? njW[k * 256 + (c - 256)]
                            : msgW[k * 128 + (c - 512)];
        bcat[idx] = v;
    }
    // ewfrag[((c*2+s)*64+lane)*8+i] = bf16(eW[k][col]), k=s*32+(lane>>4)*8+i, col=c*16+(lane&15)
    if (idx < 16384) {
        int c = idx >> 10, s = (idx >> 9) & 1, ln = (idx >> 3) & 63, i = idx & 7;
        int k = s * 32 + ((ln >> 4) << 3) + i;
        int col = c * 16 + (ln & 15);
        ewfrag[idx] = f2b(eW[k * 256 + col]);
    }
    if (idx < 8192) {
        int c = idx >> 10, s = (idx >> 9) & 1, ln = (idx >> 3) & 63, i = idx & 7;
        int k = s * 32 + ((ln >> 4) << 3) + i;
        int col = c * 16 + (ln & 15);
        msgfrag[idx] = f2b(msgW[(128 + k) * 128 + col]);
    }
    if (blockIdx.x == 0 && threadIdx.x < 256) {
        int c = threadIdx.x;
        btot[c] = nib[c] + njb[c] + eb[c];
    }
}

// shared inner GEMM tile (f32 VALU): acc[4][8] += A[4r][64k] * B[64k][8c]
__device__ __forceinline__ void gemm_tile(const float* Al, int astride, int acol0,
                                          const float* Bl, int trow, int tcol,
                                          float acc[4][8]) {
    for (int k4 = 0; k4 < 64; k4 += 4) {
        float ar[4][4];
#pragma unroll
        for (int r = 0; r < 4; ++r)
            *(float4*)ar[r] = *(const float4*)&Al[(trow * 4 + r) * astride + acol0 + k4];
#pragma unroll
        for (int kk = 0; kk < 4; ++kk) {
            float4 b0 = *(const float4*)&Bl[(k4 + kk) * 128 + tcol * 8];
            float4 b1 = *(const float4*)&Bl[(k4 + kk) * 128 + tcol * 8 + 4];
            float bv[8] = {b0.x, b0.y, b0.z, b0.w, b1.x, b1.y, b1.z, b1.w};
#pragma unroll
            for (int r = 0; r < 4; ++r) {
                float av = ar[r][kk];
#pragma unroll
                for (int j = 0; j < 8; ++j) acc[r][j] = fmaf(av, bv[j], acc[r][j]);
            }
        }
    }
}

// ---- K1: pre = node_features @ bcat; cols 0..511 -> bf16, 512..639 -> f32 ----
__global__ __launch_bounds__(256) void k_node_pre(const float* __restrict__ nf,
                                                  const float* __restrict__ bcat,
                                                  u16* __restrict__ pre16,
                                                  float* __restrict__ premsg) {
    __shared__ float Al[64 * 128];
    __shared__ float Bl[64 * 128];
    int t = threadIdx.x, n0 = blockIdx.x * 64;
    int trow = t >> 4, tcol = t & 15;
#pragma unroll
    for (int q = 0; q < 8; ++q) {
        int g = t + 256 * q;
        int i = g >> 5, k4 = (g & 31) * 4;
        int n = n0 + i;
        float4 v = make_float4(0.f, 0.f, 0.f, 0.f);
        if (n < 25000) v = *(const float4*)&nf[(size_t)n * 128 + k4];
        *(float4*)&Al[i * 128 + k4] = v;
    }
    for (int cc = 0; cc < 5; ++cc) {
        float acc[4][8] = {};
        for (int kh = 0; kh < 2; ++kh) {
            __syncthreads();
#pragma unroll
            for (int q = 0; q < 8; ++q) {
                int g = t + 256 * q;
                int k = g >> 5, c4 = (g & 31) * 4;
                *(float4*)&Bl[k * 128 + c4] =
                    *(const float4*)&bcat[(kh * 64 + k) * 640 + cc * 128 + c4];
            }
            __syncthreads();
            gemm_tile(Al, 128, kh * 64, Bl, trow, tcol, acc);
        }
#pragma unroll
        for (int r = 0; r < 4; ++r) {
            int n = n0 + trow * 4 + r;
            if (n < 25000) {
                if (cc < 4) {
                    u16x8 h8;
#pragma unroll
                    for (int j = 0; j < 8; ++j) h8[j] = f2b(acc[r][j]);
                    *(u16x8*)&pre16[(size_t)n * 512 + cc * 128 + tcol * 8] = h8;
                } else {
                    *(float4*)&premsg[(size_t)n * 128 + tcol * 8] =
                        make_float4(acc[r][0], acc[r][1], acc[r][2], acc[r][3]);
                    *(float4*)&premsg[(size_t)n * 128 + tcol * 8 + 4] =
                        make_float4(acc[r][4], acc[r][5], acc[r][6], acc[r][7]);
                }
            }
        }
        __syncthreads();
    }
}

// ---- K2a: histogram of dst ----
__global__ void k_hist(const int* __restrict__ eidx, int* __restrict__ count) {
    int e = blockIdx.x * 256 + threadIdx.x;
    if (e < 400000) atomicAdd(&count[eidx[e]], 1);
}

// ---- K2b: exclusive scan (single block) count -> cursor, rowst ----
__global__ __launch_bounds__(1024) void k_scan(const int* __restrict__ count,
                                               int* __restrict__ cursor,
                                               int* __restrict__ rowst) {
    __shared__ int sums[1024];
    int t = threadIdx.x;
    int base = t * 25;
    int v[25];
    int local = 0;
#pragma unroll
    for (int i = 0; i < 25; ++i) {
        int idx = base + i;
        int c = (idx < 25000) ? count[idx] : 0;
        v[i] = local;
        local += c;
    }
    sums[t] = local;
    __syncthreads();
    for (int off = 1; off < 1024; off <<= 1) {
        int x = (t >= off) ? sums[t - off] : 0;
        __syncthreads();
        sums[t] += x;
        __syncthreads();
    }
    int prefix = (t == 0) ? 0 : sums[t - 1];
#pragma unroll
    for (int i = 0; i < 25; ++i) {
        int idx = base + i;
        if (idx < 25000) { cursor[idx] = prefix + v[i]; rowst[idx] = prefix + v[i]; }
    }
}

// ---- K2c: scatter edge ids + src into dst-sorted order ----
__global__ void k_scatter(const int* __restrict__ eidx, int* __restrict__ cursor,
                          int* __restrict__ perm, int* __restrict__ srcs) {
    int e = blockIdx.x * 256 + threadIdx.x;
    if (e < 400000) {
        int d = eidx[e];
        int p = atomicAdd(&cursor[d], 1);
        perm[p] = e;
        srcs[p] = eidx[400000 + e];
    }
}

// ---- K3: FUSED per-node flash-GAT: logits + online softmax + messages + agg ----
// One wave per destination node. Swapped MFMA layout: lane l handles edge
// slot le=l&15 of the tile, cols colb = c*16 + g4 .. +3 (g4=(l>>4)*4).
__global__ __launch_bounds__(256) void k_fused(
        const float* __restrict__ ef, const int* __restrict__ perm,
        const int* __restrict__ srcs, const int* __restrict__ rowst,
        const int* __restrict__ count,
        const u16* __restrict__ ewfrag, const u16* __restrict__ msgfrag,
        const u16* __restrict__ pre16, const float* __restrict__ premsg,
        const float* __restrict__ btot, const float* __restrict__ aproj,
        float* __restrict__ agg) {
    int n = (blockIdx.x * 256 + threadIdx.x) >> 6;
    if (n >= 25000) return;
    int l = threadIdx.x & 63;
    int le = l & 15, g4 = (l >> 4) << 2;
    int deg = count[n];
    if (deg == 0) {
        if (le == 0) {
            f4 z = {0.f, 0.f, 0.f, 0.f};
#pragma unroll
            for (int c = 0; c < 8; ++c)
                *(f4*)&agg[(size_t)n * 128 + c * 16 + g4] = z;
        }
        return;
    }
    int rs = rowst[n];
    const u16* pni = &pre16[(size_t)n * 512 + g4];

    float m0 = -3.0e38f, m1 = -3.0e38f, s0 = 0.f, s1 = 0.f;
    f4 O[8];
#pragma unroll
    for (int c = 0; c < 8; ++c) O[c] = (f4){0.f, 0.f, 0.f, 0.f};

    for (int t0 = 0; t0 < deg; t0 += 16) {
        int q = t0 + le;
        bool valid = q < deg;
        int p = rs + (valid ? q : deg - 1);
        int e = perm[p];
        int es = srcs[p];

        // issue all loads for this tile up front (MLP)
        const float* bp = &ef[(size_t)e * 64 + (l >> 4) * 8];
        float4 b00 = *(const float4*)bp;
        float4 b01 = *(const float4*)(bp + 4);
        float4 b10 = *(const float4*)(bp + 32);
        float4 b11 = *(const float4*)(bp + 36);

        const u16* pnj = &pre16[(size_t)es * 512 + 256 + g4];
        u16x4 pj[16];
#pragma unroll
        for (int c = 0; c < 16; ++c) pj[c] = *(const u16x4*)&pnj[c * 16];
        const float* pmp = &premsg[(size_t)es * 128 + g4];
        f4 pmv[8];
#pragma unroll
        for (int c = 0; c < 8; ++c) pmv[c] = *(const f4*)&pmp[c * 16];
        u16x4 pi[16];
#pragma unroll
        for (int c = 0; c < 16; ++c) pi[c] = *(const u16x4*)&pni[c * 16];

        bf8 bf0 = pack8(b00, b01), bf1 = pack8(b10, b11);  // ef^T B-frag

        // ---- logits ----
        float part0 = 0.f, part1 = 0.f;
#pragma unroll
        for (int c = 0; c < 16; ++c) {
            bf8 wa0 = *(const bf8*)&ewfrag[(size_t)((c * 2 + 0) * 64 + l) * 8];
            bf8 wa1 = *(const bf8*)&ewfrag[(size_t)((c * 2 + 1) * 64 + l) * 8];
            f4 acc = {0.f, 0.f, 0.f, 0.f};
            acc = __builtin_amdgcn_mfma_f32_16x16x32_bf16(wa0, bf0, acc, 0, 0, 0);
            acc = __builtin_amdgcn_mfma_f32_16x16x32_bf16(wa1, bf1, acc, 0, 0, 0);
            int colb = c * 16 + g4;
            f4 bt4 = *(const f4*)&btot[colb];
            f4 ap4 = *(const f4*)&aproj[colb];
            float pp = 0.f;
#pragma unroll
            for (int r = 0; r < 4; ++r) {
                float hid = acc[r] + b2f(pi[c][r]) + b2f(pj[c][r]) + bt4[r];
                hid = hid >= 0.f ? hid : NEG * hid;
                pp = fmaf(hid, ap4[r], pp);
            }
            if (c < 8) part0 += pp; else part1 += pp;
        }
        part0 += __shfl_xor(part0, 16); part0 += __shfl_xor(part0, 32);
        part1 += __shfl_xor(part1, 16); part1 += __shfl_xor(part1, 32);
        if (!valid) { part0 = -3.0e38f; part1 = -3.0e38f; }

        // ---- online softmax update (per head, wave-local) ----
        float tm0 = part0, tm1 = part1;
#pragma unroll
        for (int mm = 1; mm < 16; mm <<= 1) {
            tm0 = fmaxf(tm0, __shfl_xor(tm0, mm));
            tm1 = fmaxf(tm1, __shfl_xor(tm1, mm));
        }
        float nm0 = fmaxf(m0, tm0), nm1 = fmaxf(m1, tm1);
        float f0 = __expf(m0 - nm0), f1 = __expf(m1 - nm1);
        float p0 = valid ? __expf(part0 - nm0) : 0.f;
        float p1 = valid ? __expf(part1 - nm1) : 0.f;
        float sp0 = p0, sp1 = p1;
#pragma unroll
        for (int mm = 1; mm < 16; mm <<= 1) {
            sp0 += __shfl_xor(sp0, mm);
            sp1 += __shfl_xor(sp1, mm);
        }
        s0 = s0 * f0 + sp0;
        s1 = s1 * f1 + sp1;
        m0 = nm0; m1 = nm1;
#pragma unroll
        for (int c = 0; c < 8; ++c) {
            float f = (c < 4) ? f0 : f1;
#pragma unroll
            for (int r = 0; r < 4; ++r) O[c][r] *= f;
        }

        // ---- messages (ef frags reused!) + weighted accumulate ----
#pragma unroll
        for (int c = 0; c < 8; ++c) {
            bf8 wa0 = *(const bf8*)&msgfrag[(size_t)((c * 2 + 0) * 64 + l) * 8];
            bf8 wa1 = *(const bf8*)&msgfrag[(size_t)((c * 2 + 1) * 64 + l) * 8];
            f4 acc = {0.f, 0.f, 0.f, 0.f};
            acc = __builtin_amdgcn_mfma_f32_16x16x32_bf16(wa0, bf0, acc, 0, 0, 0);
            acc = __builtin_amdgcn_mfma_f32_16x16x32_bf16(wa1, bf1, acc, 0, 0, 0);
            float wt = (c < 4) ? p0 : p1;
#pragma unroll
            for (int r = 0; r < 4; ++r)
                O[c][r] = fmaf(wt, acc[r] + pmv[c][r], O[c][r]);
        }
    }

    // ---- finalize: /s, cross-lane reduce over le, store ----
    float inv0 = 1.f / s0, inv1 = 1.f / s1;
#pragma unroll
    for (int c = 0; c < 8; ++c) {
        float inv = (c < 4) ? inv0 : inv1;
#pragma unroll
        for (int r = 0; r < 4; ++r) {
            float v = O[c][r] * inv;
#pragma unroll
            for (int mm = 1; mm < 16; mm <<= 1) v += __shfl_xor(v, mm);
            O[c][r] = v;
        }
    }
    if (le == 0) {
#pragma unroll
        for (int c = 0; c < 8; ++c)
            *(f4*)&agg[(size_t)n * 128 + c * 16 + g4] = O[c];
    }
}

// ---- K6: out = (agg + msg_b*[deg>0]) @ out_W + out_b ----
__global__ __launch_bounds__(256) void k_out(
        const float* __restrict__ agg, const int* __restrict__ count,
        const float* __restrict__ msgb, const float* __restrict__ outW,
        const float* __restrict__ outb, float* __restrict__ out) {
    __shared__ float Al[64 * 128];
    __shared__ float Bl[64 * 128];
    int t = threadIdx.x, n0 = blockIdx.x * 64;
    int trow = t >> 4, tcol = t & 15;
#pragma unroll
    for (int q = 0; q < 8; ++q) {
        int g = t + 256 * q;
        int i = g >> 5, k4 = (g & 31) * 4;
        int n = n0 + i;
        float4 v = make_float4(0.f, 0.f, 0.f, 0.f);
        if (n < 25000) {
            v = *(const float4*)&agg[(size_t)n * 128 + k4];
            if (count[n] > 0) {
                float4 mb = *(const float4*)&msgb[k4];
                v.x += mb.x; v.y += mb.y; v.z += mb.z; v.w += mb.w;
            }
        }
        *(float4*)&Al[i * 128 + k4] = v;
    }
    float acc[4][8] = {};
    for (int kh = 0; kh < 2; ++kh) {
        __syncthreads();
#pragma unroll
        for (int q = 0; q < 8; ++q) {
            int g = t + 256 * q;
            int k = g >> 5, c4 = (g & 31) * 4;
            *(float4*)&Bl[k * 128 + c4] = *(const float4*)&outW[(kh * 64 + k) * 128 + c4];
        }
        __syncthreads();
        gemm_tile(Al, 128, kh * 64, Bl, trow, tcol, acc);
    }
    float ob[8];
    *(float4*)ob = *(const float4*)&outb[tcol * 8];
    *(float4*)(ob + 4) = *(const float4*)&outb[tcol * 8 + 4];
#pragma unroll
    for (int r = 0; r < 4; ++r) {
        int n = n0 + trow * 4 + r;
        if (n < 25000) {
            *(float4*)&out[(size_t)n * 128 + tcol * 8] =
                make_float4(acc[r][0] + ob[0], acc[r][1] + ob[1], acc[r][2] + ob[2], acc[r][3] + ob[3]);
            *(float4*)&out[(size_t)n * 128 + tcol * 8 + 4] =
                make_float4(acc[r][4] + ob[4], acc[r][5] + ob[5], acc[r][6] + ob[6], acc[r][7] + ob[7]);
        }
    }
}

extern "C" void kernel_launch(void* const* d_in, const int* in_sizes, int n_in,
                              void* d_out, int out_size, void* d_ws, size_t ws_size,
                              hipStream_t stream) {
    const float* nf    = (const float*)d_in[0];
    const float* ef    = (const float*)d_in[1];
    const int*   eidx  = (const int*)d_in[2];
    const float* niW   = (const float*)d_in[3];
    const float* nib   = (const float*)d_in[4];
    const float* njW   = (const float*)d_in[5];
    const float* njb   = (const float*)d_in[6];
    const float* eW    = (const float*)d_in[7];
    const float* eb    = (const float*)d_in[8];
    const float* aproj = (const float*)d_in[9];
    const float* msgW  = (const float*)d_in[10];
    const float* msgb  = (const float*)d_in[11];
    const float* outW  = (const float*)d_in[12];
    const float* outb  = (const float*)d_in[13];

    float* ws = (float*)d_ws;
    float* premsg    = ws + OFF_PREM;
    u16*   pre16     = (u16*)(ws + OFF_P16);
    float* bcat      = ws + OFF_BCAT;
    float* btot      = ws + OFF_BTOT;
    float* agg       = ws + OFF_AGG;
    int*   count     = (int*)(ws + OFF_CNT);
    int*   cursor    = (int*)(ws + OFF_CUR);
    int*   rowst     = (int*)(ws + OFF_RST);
    int*   perm      = (int*)(ws + OFF_PERM);
    int*   srcs      = (int*)(ws + OFF_SRC);
    u16*   ewfrag    = (u16*)(ws + OFF_EWF);
    u16*   msgfrag   = (u16*)(ws + OFF_MWF);

    // zero count only (agg fully written by k_fused)
    hipMemsetAsync(ws + OFF_CNT, 0, (size_t)SZ_CNT * 4, stream);

    k_prep<<<320, 256, 0, stream>>>(niW, njW, msgW, eW, nib, njb, eb, bcat, btot, ewfrag, msgfrag);
    k_node_pre<<<391, 256, 0, stream>>>(nf, bcat, pre16, premsg);
    k_hist<<<1563, 256, 0, stream>>>(eidx, count);
    k_scan<<<1, 1024, 0, stream>>>(count, cursor, rowst);
    k_scatter<<<1563, 256, 0, stream>>>(eidx, cursor, perm, srcs);
    k_fused<<<6250, 256, 0, stream>>>(ef, perm, srcs, rowst, count, ewfrag, msgfrag,
                                      pre16, premsg, btot, aproj, agg);
    k_out<<<391, 256, 0, stream>>>(agg, count, msgb, outW, outb, (float*)d_out);
}

// Round 8
// 400.800 us; speedup vs baseline: 1.6347x; 1.6347x over previous
//
#include <hip/hip_runtime.h>

#define NEG 0.2f
typedef unsigned short u16;
typedef __bf16 bf8 __attribute__((ext_vector_type(8)));
typedef float f4 __attribute__((ext_vector_type(4)));
typedef u16 u16x8 __attribute__((ext_vector_type(8)));

// ---- workspace layout (in floats) ----
#define OFF_PREM  0ull                        // f32 [25000][128] msg-part of pre
#define SZ_PREM   (25000ull*128ull)
#define OFF_P16   (OFF_PREM + SZ_PREM)        // u16 [25000][512]: [0:256)=ni, [256:512)=nj (bf16)
#define SZ_P16    (25000ull*256ull)
#define OFF_BCAT  (OFF_P16 + SZ_P16)
#define SZ_BCAT   (128ull*640ull)
#define OFF_BTOT  (OFF_BCAT + SZ_BCAT)
#define SZ_BTOT   256ull
#define OFF_LOG   (OFF_BTOT + SZ_BTOT)        // logits then ex, SORTED space [p][2]
#define SZ_LOG    (2ull*400000ull)
#define OFF_MAX   (OFF_LOG + SZ_LOG)          // unsigned max-keys   (zeroed)
#define SZ_MAX    (2ull*25000ull)
#define OFF_DEN   (OFF_MAX + SZ_MAX)          // (zeroed)
#define SZ_DEN    (2ull*25000ull)
#define OFF_AGE   (OFF_DEN + SZ_DEN)          // (zeroed) aggE [25000][128] (h*64+k)
#define SZ_AGE    (25000ull*128ull)
#define OFF_AGP   (OFF_AGE + SZ_AGE)          // (zeroed) aggP [25000][128]
#define SZ_AGP    (25000ull*128ull)
#define OFF_CNT   (OFF_AGP + SZ_AGP)          // (zeroed)
#define SZ_CNT    25000ull
#define OFF_CUR   (OFF_CNT + SZ_CNT)
#define SZ_CUR    25000ull
#define OFF_PERM  (OFF_CUR + SZ_CUR)
#define SZ_PERM   400000ull
#define OFF_DST   (OFF_PERM + SZ_PERM)
#define SZ_DST    400000ull
#define OFF_SRC   (OFF_DST + SZ_DST)
#define SZ_SRC    400000ull
#define OFF_EWF   (OFF_SRC + SZ_SRC)          // u16[16384] MFMA-frag-packed e_W
#define SZ_EWF    8192ull
#define OFF_M1    (OFF_EWF + SZ_EWF)          // f32 [128][128] = msgWe @ outW (per-head blocks)
#define SZ_M1     16384ull
#define OFF_MBW   (OFF_M1 + SZ_M1)            // f32 [128] = msgb @ outW
#define SZ_MBW    128ull

__device__ __forceinline__ unsigned fkey(float f) {
    unsigned u = __float_as_uint(f);
    return (u & 0x80000000u) ? ~u : (u | 0x80000000u);
}
__device__ __forceinline__ float keyf(unsigned k) {
    unsigned u = (k & 0x80000000u) ? (k & 0x7fffffffu) : ~k;
    return __uint_as_float(u);
}
__device__ __forceinline__ u16 f2b(float f) {
    unsigned u = __float_as_uint(f);
    return (u16)((u + 0x7FFFu + ((u >> 16) & 1u)) >> 16);
}
__device__ __forceinline__ float b2f(u16 v) {
    return __uint_as_float(((unsigned)v) << 16);
}
__device__ __forceinline__ bf8 pack8(float4 a, float4 b) {
    union { u16 u[8]; bf8 v; } x;
    x.u[0] = f2b(a.x); x.u[1] = f2b(a.y); x.u[2] = f2b(a.z); x.u[3] = f2b(a.w);
    x.u[4] = f2b(b.x); x.u[5] = f2b(b.y); x.u[6] = f2b(b.z); x.u[7] = f2b(b.w);
    return x.v;
}

// ---- K0: concat weights; total bias; ewfrag packing; M1 = We@outW; mbW = msgb@outW ----
__global__ void k_prep(const float* __restrict__ niW, const float* __restrict__ njW,
                       const float* __restrict__ msgW, const float* __restrict__ eW,
                       const float* __restrict__ nib, const float* __restrict__ njb,
                       const float* __restrict__ eb, const float* __restrict__ msgb,
                       const float* __restrict__ outW,
                       float* __restrict__ bcat, float* __restrict__ btot,
                       u16* __restrict__ ewfrag, float* __restrict__ M1,
                       float* __restrict__ mbW) {
    int idx = blockIdx.x * 256 + threadIdx.x;
    if (idx < 128 * 640) {
        int k = idx / 640, c = idx % 640;
        float v = (c < 256) ? niW[k * 256 + c]
                : (c < 512) ? njW[k * 256 + (c - 256)]
                            : msgW[k * 128 + (c - 512)];
        bcat[idx] = v;
    }
    // ewfrag[((c*2+s)*64+lane)*8+i] = bf16(eW[k][col]), k=s*32+(lane>>4)*8+i, col=c*16+(lane&15)
    if (idx < 16384) {
        int c = idx >> 10, s = (idx >> 9) & 1, ln = (idx >> 3) & 63, i = idx & 7;
        int k = s * 32 + ((ln >> 4) << 3) + i;
        int col = c * 16 + (ln & 15);
        ewfrag[idx] = f2b(eW[k * 256 + col]);
    }
    // M1[h*64+k][c] = sum_j msgW[128+k][h*64+j] * outW[h*64+j][c]
    if (idx < 16384) {
        int r = idx >> 7, c = idx & 127;
        int h = r >> 6, k = r & 63;
        float s = 0.f;
        for (int j = 0; j < 64; ++j)
            s = fmaf(msgW[(size_t)(128 + k) * 128 + h * 64 + j],
                     outW[(size_t)(h * 64 + j) * 128 + c], s);
        M1[idx] = s;
    }
    if (idx < 128) {
        float s = 0.f;
        for (int m = 0; m < 128; ++m) s = fmaf(msgb[m], outW[(size_t)m * 128 + idx], s);
        mbW[idx] = s;
    }
    if (blockIdx.x == 0 && threadIdx.x < 256) {
        int c = threadIdx.x;
        btot[c] = nib[c] + njb[c] + eb[c];
    }
}

// shared inner GEMM tile (f32 VALU): acc[4][8] += A[4r][64k] * B[64k][8c]
__device__ __forceinline__ void gemm_tile(const float* Al, int astride, int acol0,
                                          const float* Bl, int trow, int tcol,
                                          float acc[4][8]) {
    for (int k4 = 0; k4 < 64; k4 += 4) {
        float ar[4][4];
#pragma unroll
        for (int r = 0; r < 4; ++r)
            *(float4*)ar[r] = *(const float4*)&Al[(trow * 4 + r) * astride + acol0 + k4];
#pragma unroll
        for (int kk = 0; kk < 4; ++kk) {
            float4 b0 = *(const float4*)&Bl[(k4 + kk) * 128 + tcol * 8];
            float4 b1 = *(const float4*)&Bl[(k4 + kk) * 128 + tcol * 8 + 4];
            float bv[8] = {b0.x, b0.y, b0.z, b0.w, b1.x, b1.y, b1.z, b1.w};
#pragma unroll
            for (int r = 0; r < 4; ++r) {
                float av = ar[r][kk];
#pragma unroll
                for (int j = 0; j < 8; ++j) acc[r][j] = fmaf(av, bv[j], acc[r][j]);
            }
        }
    }
}

// ---- K1: pre = node_features @ bcat; cols 0..511 -> bf16, 512..639 -> f32 ----
__global__ __launch_bounds__(256) void k_node_pre(const float* __restrict__ nf,
                                                  const float* __restrict__ bcat,
                                                  u16* __restrict__ pre16,
                                                  float* __restrict__ premsg) {
    __shared__ float Al[64 * 128];
    __shared__ float Bl[64 * 128];
    int t = threadIdx.x, n0 = blockIdx.x * 64;
    int trow = t >> 4, tcol = t & 15;
#pragma unroll
    for (int q = 0; q < 8; ++q) {
        int g = t + 256 * q;
        int i = g >> 5, k4 = (g & 31) * 4;
        int n = n0 + i;
        float4 v = make_float4(0.f, 0.f, 0.f, 0.f);
        if (n < 25000) v = *(const float4*)&nf[(size_t)n * 128 + k4];
        *(float4*)&Al[i * 128 + k4] = v;
    }
    for (int cc = 0; cc < 5; ++cc) {
        float acc[4][8] = {};
        for (int kh = 0; kh < 2; ++kh) {
            __syncthreads();
#pragma unroll
            for (int q = 0; q < 8; ++q) {
                int g = t + 256 * q;
                int k = g >> 5, c4 = (g & 31) * 4;
                *(float4*)&Bl[k * 128 + c4] =
                    *(const float4*)&bcat[(kh * 64 + k) * 640 + cc * 128 + c4];
            }
            __syncthreads();
            gemm_tile(Al, 128, kh * 64, Bl, trow, tcol, acc);
        }
#pragma unroll
        for (int r = 0; r < 4; ++r) {
            int n = n0 + trow * 4 + r;
            if (n < 25000) {
                if (cc < 4) {
                    u16x8 h8;
#pragma unroll
                    for (int j = 0; j < 8; ++j) h8[j] = f2b(acc[r][j]);
                    *(u16x8*)&pre16[(size_t)n * 512 + cc * 128 + tcol * 8] = h8;
                } else {
                    *(float4*)&premsg[(size_t)n * 128 + tcol * 8] =
                        make_float4(acc[r][0], acc[r][1], acc[r][2], acc[r][3]);
                    *(float4*)&premsg[(size_t)n * 128 + tcol * 8 + 4] =
                        make_float4(acc[r][4], acc[r][5], acc[r][6], acc[r][7]);
                }
            }
        }
        __syncthreads();
    }
}

// ---- K2a: histogram of dst ----
__global__ void k_hist(const int* __restrict__ eidx, int* __restrict__ count) {
    int e = blockIdx.x * 256 + threadIdx.x;
    if (e < 400000) atomicAdd(&count[eidx[e]], 1);
}

// ---- K2b: exclusive scan (single block) count -> cursor ----
__global__ __launch_bounds__(1024) void k_scan(const int* __restrict__ count,
                                               int* __restrict__ cursor) {
    __shared__ int sums[1024];
    int t = threadIdx.x;
    int base = t * 25;
    int v[25];
    int local = 0;
#pragma unroll
    for (int i = 0; i < 25; ++i) {
        int idx = base + i;
        int c = (idx < 25000) ? count[idx] : 0;
        v[i] = local;
        local += c;
    }
    sums[t] = local;
    __syncthreads();
    for (int off = 1; off < 1024; off <<= 1) {
        int x = (t >= off) ? sums[t - off] : 0;
        __syncthreads();
        sums[t] += x;
        __syncthreads();
    }
    int prefix = (t == 0) ? 0 : sums[t - 1];
#pragma unroll
    for (int i = 0; i < 25; ++i) {
        int idx = base + i;
        if (idx < 25000) cursor[idx] = prefix + v[i];
    }
}

// ---- K2c: scatter edge ids + dst/src into dst-sorted order ----
__global__ void k_scatter(const int* __restrict__ eidx, int* __restrict__ cursor,
                          int* __restrict__ perm, int* __restrict__ dsts,
                          int* __restrict__ srcs) {
    int e = blockIdx.x * 256 + threadIdx.x;
    if (e < 400000) {
        int d = eidx[e];
        int p = atomicAdd(&cursor[d], 1);
        perm[p] = e;
        dsts[p] = d;
        srcs[p] = eidx[400000 + e];
    }
}

// ---- K3: edge logits via bf16 MFMA over dst-sorted edges + atomic max (R4-proven) ----
__global__ __launch_bounds__(256) void k_edge_logits(
        const float* __restrict__ ef, const int* __restrict__ perm,
        const int* __restrict__ dsts, const int* __restrict__ srcs,
        const u16* __restrict__ ewfrag, const u16* __restrict__ pre16,
        const float* __restrict__ btot, const float* __restrict__ aproj,
        float* __restrict__ logits_s, unsigned* __restrict__ maxkey) {
    __shared__ int eperm[64], dstl[64], srcl[64];
    int t = threadIdx.x;
    int w = t >> 6, l = t & 63;
    int p0 = blockIdx.x * 64;
    int row = l & 15, kb = l >> 4;

    if (t < 64) {
        eperm[t] = perm[p0 + t];
        dstl[t] = dsts[p0 + t];
        srcl[t] = srcs[p0 + t];
    }
    __syncthreads();

    int ea = eperm[w * 16 + row];
    const float* ap = &ef[(size_t)ea * 64 + kb * 8];
    float4 a00 = *(const float4*)ap;
    float4 a01 = *(const float4*)(ap + 4);
    float4 a10 = *(const float4*)(ap + 32);
    float4 a11 = *(const float4*)(ap + 36);
    bf8 a0 = pack8(a00, a01), a1 = pack8(a10, a11);

    int ed[4], es[4];
#pragma unroll
    for (int r = 0; r < 4; ++r) {
        int i4 = w * 16 + kb * 4 + r;
        ed[r] = dstl[i4];
        es[r] = srcl[i4];
    }

    float part0[4] = {0.f, 0.f, 0.f, 0.f}, part1[4] = {0.f, 0.f, 0.f, 0.f};
#pragma unroll
    for (int c = 0; c < 16; ++c) {
        bf8 b0 = *(const bf8*)&ewfrag[(size_t)((c * 2 + 0) * 64 + l) * 8];
        bf8 b1 = *(const bf8*)&ewfrag[(size_t)((c * 2 + 1) * 64 + l) * 8];
        f4 acc = {0.f, 0.f, 0.f, 0.f};
        acc = __builtin_amdgcn_mfma_f32_16x16x32_bf16(a0, b0, acc, 0, 0, 0);
        acc = __builtin_amdgcn_mfma_f32_16x16x32_bf16(a1, b1, acc, 0, 0, 0);
        int col = c * 16 + row;
        float bt = btot[col], apj = aproj[col];
#pragma unroll
        for (int r = 0; r < 4; ++r) {
            float pi = b2f(pre16[(size_t)ed[r] * 512 + col]);
            float pj = b2f(pre16[(size_t)es[r] * 512 + 256 + col]);
            float hid = acc[r] + pi + pj + bt;
            hid = hid >= 0.f ? hid : NEG * hid;
            if (c < 8) part0[r] = fmaf(hid, apj, part0[r]);
            else       part1[r] = fmaf(hid, apj, part1[r]);
        }
    }
#pragma unroll
    for (int m = 1; m < 16; m <<= 1) {
#pragma unroll
        for (int r = 0; r < 4; ++r) {
            part0[r] += __shfl_xor(part0[r], m);
            part1[r] += __shfl_xor(part1[r], m);
        }
    }
    if (row == 0) {
#pragma unroll
        for (int r = 0; r < 4; ++r) {
            int p = p0 + w * 16 + kb * 4 + r;
            logits_s[(size_t)p * 2 + 0] = part0[r];
            logits_s[(size_t)p * 2 + 1] = part1[r];
            atomicMax(&maxkey[ed[r] * 2 + 0], fkey(part0[r]));
            atomicMax(&maxkey[ed[r] * 2 + 1], fkey(part1[r]));
        }
    }
}

// ---- K4: ex = exp(logit - max); denom += ex  (sorted space) ----
__global__ void k_soft(const int* __restrict__ dsts, float* __restrict__ logits_s,
                       const unsigned* __restrict__ maxkey, float* __restrict__ denom) {
    int idx = blockIdx.x * 256 + threadIdx.x;
    if (idx >= 800000) return;
    int p = idx >> 1, h = idx & 1;
    int d = dsts[p];
    float m = keyf(maxkey[d * 2 + h]);
    float ex = __expf(logits_s[idx] - m);
    logits_s[idx] = ex;
    atomicAdd(&denom[d * 2 + h], ex);
}

// ---- K5: streaming weighted segmented-sum (NO MFMA):
// aggE[d][h*64+k] += attn_h * ef[e][k];  aggP[d][c] += attn_{c>>6} * premsg[src][c]
__global__ __launch_bounds__(256) void k_msgagg(
        const float* __restrict__ ef, const int* __restrict__ perm,
        const int* __restrict__ dsts, const int* __restrict__ srcs,
        const float* __restrict__ exs, const float* __restrict__ denom,
        const float* __restrict__ premsg,
        float* __restrict__ aggE, float* __restrict__ aggP) {
    __shared__ float efL[64 * 68];
    __shared__ float pmL[64 * 132];
    __shared__ float attL[64][2];
    __shared__ int dstl[64], el[64], sl[64];
    int t = threadIdx.x, p0 = blockIdx.x * 64;

    if (t < 64) {
        int p = p0 + t;
        int d = dsts[p];
        dstl[t] = d;
        el[t] = perm[p];
        sl[t] = srcs[p];
        attL[t][0] = exs[(size_t)p * 2 + 0] / denom[d * 2 + 0];
        attL[t][1] = exs[(size_t)p * 2 + 1] / denom[d * 2 + 1];
    }
    __syncthreads();
    // ef tile: 64 rows x 64 f32 (16 float4/row)
#pragma unroll
    for (int q = 0; q < 4; ++q) {
        int g = t + 256 * q;
        int r = g >> 4, ch = g & 15;
        *(float4*)&efL[r * 68 + ch * 4] = *(const float4*)&ef[(size_t)el[r] * 64 + ch * 4];
    }
    // premsg tile: 64 rows x 128 f32 (32 float4/row)
#pragma unroll
    for (int q = 0; q < 8; ++q) {
        int g = t + 256 * q;
        int r = g >> 5, ch = g & 31;
        *(float4*)&pmL[r * 132 + ch * 4] = *(const float4*)&premsg[(size_t)sl[r] * 128 + ch * 4];
    }
    __syncthreads();

    // segmented reduce: thread t = output column (0..127 -> aggE, 128..255 -> aggP)
    bool isE = t < 128;
    int cc = isE ? t : (t - 128);
    int h = cc >> 6;
    int k = cc & 63;
    float* base = isE ? aggE : aggP;
    int cur = dstl[0];
    float sum = 0.f;
    for (int r = 0; r < 64; ++r) {
        int d = dstl[r];
        if (d != cur) {
            atomicAdd(&base[(size_t)cur * 128 + cc], sum);
            sum = 0.f;
            cur = d;
        }
        float v = isE ? efL[r * 68 + k] : pmL[r * 132 + cc];
        sum = fmaf(attL[r][h], v, sum);
    }
    atomicAdd(&base[(size_t)cur * 128 + cc], sum);
}

// ---- K6: out = aggE@M1 + aggP@outW + outb + has*(msgb@outW) ----
__global__ __launch_bounds__(256) void k_out(
        const float* __restrict__ aggE, const float* __restrict__ aggP,
        const int* __restrict__ count, const float* __restrict__ M1,
        const float* __restrict__ outW, const float* __restrict__ mbW,
        const float* __restrict__ outb, float* __restrict__ out) {
    __shared__ float Al[64 * 128];
    __shared__ float Bl[64 * 128];
    int t = threadIdx.x, n0 = blockIdx.x * 64;
    int trow = t >> 4, tcol = t & 15;
    float acc[4][8] = {};
    for (int src = 0; src < 2; ++src) {
        const float* Amat = src == 0 ? aggE : aggP;
        const float* Bmat = src == 0 ? M1 : outW;
        __syncthreads();
#pragma unroll
        for (int q = 0; q < 8; ++q) {
            int g = t + 256 * q;
            int i = g >> 5, k4 = (g & 31) * 4;
            int n = n0 + i;
            float4 v = make_float4(0.f, 0.f, 0.f, 0.f);
            if (n < 25000) v = *(const float4*)&Amat[(size_t)n * 128 + k4];
            *(float4*)&Al[i * 128 + k4] = v;
        }
        for (int kh = 0; kh < 2; ++kh) {
            __syncthreads();
#pragma unroll
            for (int q = 0; q < 8; ++q) {
                int g = t + 256 * q;
                int k = g >> 5, c4 = (g & 31) * 4;
                *(float4*)&Bl[k * 128 + c4] = *(const float4*)&Bmat[(kh * 64 + k) * 128 + c4];
            }
            __syncthreads();
            gemm_tile(Al, 128, kh * 64, Bl, trow, tcol, acc);
        }
    }
    float ob[8], mb[8];
    *(float4*)ob = *(const float4*)&outb[tcol * 8];
    *(float4*)(ob + 4) = *(const float4*)&outb[tcol * 8 + 4];
    *(float4*)mb = *(const float4*)&mbW[tcol * 8];
    *(float4*)(mb + 4) = *(const float4*)&mbW[tcol * 8 + 4];
#pragma unroll
    for (int r = 0; r < 4; ++r) {
        int n = n0 + trow * 4 + r;
        if (n < 25000) {
            float hs = (count[n] > 0) ? 1.f : 0.f;
            float4 o0, o1;
            o0.x = acc[r][0] + ob[0] + hs * mb[0];
            o0.y = acc[r][1] + ob[1] + hs * mb[1];
            o0.z = acc[r][2] + ob[2] + hs * mb[2];
            o0.w = acc[r][3] + ob[3] + hs * mb[3];
            o1.x = acc[r][4] + ob[4] + hs * mb[4];
            o1.y = acc[r][5] + ob[5] + hs * mb[5];
            o1.z = acc[r][6] + ob[6] + hs * mb[6];
            o1.w = acc[r][7] + ob[7] + hs * mb[7];
            *(float4*)&out[(size_t)n * 128 + tcol * 8] = o0;
            *(float4*)&out[(size_t)n * 128 + tcol * 8 + 4] = o1;
        }
    }
}

extern "C" void kernel_launch(void* const* d_in, const int* in_sizes, int n_in,
                              void* d_out, int out_size, void* d_ws, size_t ws_size,
                              hipStream_t stream) {
    const float* nf    = (const float*)d_in[0];
    const float* ef    = (const float*)d_in[1];
    const int*   eidx  = (const int*)d_in[2];
    const float* niW   = (const float*)d_in[3];
    const float* nib   = (const float*)d_in[4];
    const float* njW   = (const float*)d_in[5];
    const float* njb   = (const float*)d_in[6];
    const float* eW    = (const float*)d_in[7];
    const float* eb    = (const float*)d_in[8];
    const float* aproj = (const float*)d_in[9];
    const float* msgW  = (const float*)d_in[10];
    const float* msgb  = (const float*)d_in[11];
    const float* outW  = (const float*)d_in[12];
    const float* outb  = (const float*)d_in[13];

    float* ws = (float*)d_ws;
    float* premsg    = ws + OFF_PREM;
    u16*   pre16     = (u16*)(ws + OFF_P16);
    float* bcat      = ws + OFF_BCAT;
    float* btot      = ws + OFF_BTOT;
    float* logits_s  = ws + OFF_LOG;
    unsigned* maxkey = (unsigned*)(ws + OFF_MAX);
    float* denom     = ws + OFF_DEN;
    float* aggE      = ws + OFF_AGE;
    float* aggP      = ws + OFF_AGP;
    int*   count     = (int*)(ws + OFF_CNT);
    int*   cursor    = (int*)(ws + OFF_CUR);
    int*   perm      = (int*)(ws + OFF_PERM);
    int*   dsts      = (int*)(ws + OFF_DST);
    int*   srcs      = (int*)(ws + OFF_SRC);
    u16*   ewfrag    = (u16*)(ws + OFF_EWF);
    float* M1        = ws + OFF_M1;
    float* mbW       = ws + OFF_MBW;

    // zero maxkey + denom + aggE + aggP + count (contiguous)
    hipMemsetAsync(ws + OFF_MAX, 0,
                   (size_t)(SZ_MAX + SZ_DEN + SZ_AGE + SZ_AGP + SZ_CNT) * 4, stream);

    k_prep<<<320, 256, 0, stream>>>(niW, njW, msgW, eW, nib, njb, eb, msgb, outW,
                                    bcat, btot, ewfrag, M1, mbW);
    k_node_pre<<<391, 256, 0, stream>>>(nf, bcat, pre16, premsg);
    k_hist<<<1563, 256, 0, stream>>>(eidx, count);
    k_scan<<<1, 1024, 0, stream>>>(count, cursor);
    k_scatter<<<1563, 256, 0, stream>>>(eidx, cursor, perm, dsts, srcs);
    k_edge_logits<<<6250, 256, 0, stream>>>(ef, perm, dsts, srcs, ewfrag, pre16,
                                            btot, aproj, logits_s, maxkey);
    k_soft<<<3125, 256, 0, stream>>>(dsts, logits_s, maxkey, denom);
    k_msgagg<<<6250, 256, 0, stream>>>(ef, perm, dsts, srcs, logits_s, denom,
                                       premsg, aggE, aggP);
    k_out<<<391, 256, 0, stream>>>(aggE, aggP, count, M1, outW, mbW, outb, (float*)d_out);
}

// Round 9
// 324.320 us; speedup vs baseline: 2.0202x; 1.2358x over previous
//
#include <hip/hip_runtime.h>

#define NEG 0.2f
typedef unsigned short u16;
typedef __bf16 bf8 __attribute__((ext_vector_type(8)));
typedef float f4 __attribute__((ext_vector_type(4)));
typedef u16 u16x8 __attribute__((ext_vector_type(8)));

// ---- workspace layout (in floats) ----
#define OFF_P16   0ull                        // u16 [25000][512]: [0:256)=ni, [256:512)=nj (bf16)
#define SZ_P16    (25000ull*256ull)
#define OFF_PM16  (OFF_P16 + SZ_P16)          // u16 [25000][128] msg-part (bf16)
#define SZ_PM16   (25000ull*64ull)
#define OFF_BCF   (OFF_PM16 + SZ_PM16)        // u16[81920] MFMA-frag-packed bcat
#define SZ_BCF    40960ull
#define OFF_BTOT  (OFF_BCF + SZ_BCF)
#define SZ_BTOT   256ull
#define OFF_LOG   (OFF_BTOT + SZ_BTOT)        // logits then ex, SORTED space [p][2]
#define SZ_LOG    (2ull*400000ull)
#define OFF_MAX   (OFF_LOG + SZ_LOG)          // unsigned max-keys   (zeroed)
#define SZ_MAX    (2ull*25000ull)
#define OFF_DEN   (OFF_MAX + SZ_MAX)          // (zeroed)
#define SZ_DEN    (2ull*25000ull)
#define OFF_AGG   (OFF_DEN + SZ_DEN)          // (zeroed)
#define SZ_AGG    (25000ull*128ull)
#define OFF_CNT   (OFF_AGG + SZ_AGG)          // (zeroed)
#define SZ_CNT    25000ull
#define OFF_CUR   (OFF_CNT + SZ_CNT)
#define SZ_CUR    25000ull
#define OFF_PERM  (OFF_CUR + SZ_CUR)
#define SZ_PERM   400000ull
#define OFF_DST   (OFF_PERM + SZ_PERM)
#define SZ_DST    400000ull
#define OFF_SRC   (OFF_DST + SZ_DST)
#define SZ_SRC    400000ull
#define OFF_EWF   (OFF_SRC + SZ_SRC)          // u16[16384] MFMA-frag-packed e_W
#define SZ_EWF    8192ull
#define OFF_MWF   (OFF_EWF + SZ_EWF)          // u16[8192] MFMA-frag-packed msg_W edge half
#define SZ_MWF    4096ull

__device__ __forceinline__ unsigned fkey(float f) {
    unsigned u = __float_as_uint(f);
    return (u & 0x80000000u) ? ~u : (u | 0x80000000u);
}
__device__ __forceinline__ float keyf(unsigned k) {
    unsigned u = (k & 0x80000000u) ? (k & 0x7fffffffu) : ~k;
    return __uint_as_float(u);
}
__device__ __forceinline__ u16 f2b(float f) {
    unsigned u = __float_as_uint(f);
    return (u16)((u + 0x7FFFu + ((u >> 16) & 1u)) >> 16);
}
__device__ __forceinline__ float b2f(u16 v) {
    return __uint_as_float(((unsigned)v) << 16);
}
__device__ __forceinline__ bf8 pack8(float4 a, float4 b) {
    union { u16 u[8]; bf8 v; } x;
    x.u[0] = f2b(a.x); x.u[1] = f2b(a.y); x.u[2] = f2b(a.z); x.u[3] = f2b(a.w);
    x.u[4] = f2b(b.x); x.u[5] = f2b(b.y); x.u[6] = f2b(b.z); x.u[7] = f2b(b.w);
    return x.v;
}

// ---- K0: frag-pack bcat (ni|nj|msg), e_W, msg_W-edge-half; total bias ----
// frag layout (verified R2-R8): frag[(fi*64+lane)*8+i] = W[k][col],
//   k = s*32 + (lane>>4)*8 + i,  col = cb*16 + (lane&15),  fi = cb*nS + s
__global__ void k_prep(const float* __restrict__ niW, const float* __restrict__ njW,
                       const float* __restrict__ msgW, const float* __restrict__ eW,
                       const float* __restrict__ nib, const float* __restrict__ njb,
                       const float* __restrict__ eb,
                       u16* __restrict__ bcf, float* __restrict__ btot,
                       u16* __restrict__ ewfrag, u16* __restrict__ msgfrag) {
    int idx = blockIdx.x * 256 + threadIdx.x;
    if (idx < 81920) {   // bcat frags: 40 col-blocks x 4 k-steps (K=128)
        int fi = idx >> 9;
        int ln = (idx >> 3) & 63, i = idx & 7;
        int cb = fi >> 2, s = fi & 3;
        int k = s * 32 + ((ln >> 4) << 3) + i;
        int col = cb * 16 + (ln & 15);
        float v = (col < 256) ? niW[k * 256 + col]
                : (col < 512) ? njW[k * 256 + (col - 256)]
                              : msgW[k * 128 + (col - 512)];
        bcf[idx] = f2b(v);
    }
    if (idx < 16384) {   // e_W frags: 16 col-blocks x 2 k-steps (K=64)
        int c = idx >> 10, s = (idx >> 9) & 1, ln = (idx >> 3) & 63, i = idx & 7;
        int k = s * 32 + ((ln >> 4) << 3) + i;
        int col = c * 16 + (ln & 15);
        ewfrag[idx] = f2b(eW[k * 256 + col]);
    }
    if (idx < 8192) {    // msg_W edge-half frags: 8 col-blocks x 2 k-steps
        int c = idx >> 10, s = (idx >> 9) & 1, ln = (idx >> 3) & 63, i = idx & 7;
        int k = s * 32 + ((ln >> 4) << 3) + i;
        int col = c * 16 + (ln & 15);
        msgfrag[idx] = f2b(msgW[(128 + k) * 128 + col]);
    }
    if (idx < 256) btot[idx] = nib[idx] + njb[idx] + eb[idx];
}

// shared inner GEMM tile (f32 VALU) — used by k_out only
__device__ __forceinline__ void gemm_tile(const float* Al, int astride, int acol0,
                                          const float* Bl, int trow, int tcol,
                                          float acc[4][8]) {
    for (int k4 = 0; k4 < 64; k4 += 4) {
        float ar[4][4];
#pragma unroll
        for (int r = 0; r < 4; ++r)
            *(float4*)ar[r] = *(const float4*)&Al[(trow * 4 + r) * astride + acol0 + k4];
#pragma unroll
        for (int kk = 0; kk < 4; ++kk) {
            float4 b0 = *(const float4*)&Bl[(k4 + kk) * 128 + tcol * 8];
            float4 b1 = *(const float4*)&Bl[(k4 + kk) * 128 + tcol * 8 + 4];
            float bv[8] = {b0.x, b0.y, b0.z, b0.w, b1.x, b1.y, b1.z, b1.w};
#pragma unroll
            for (int r = 0; r < 4; ++r) {
                float av = ar[r][kk];
#pragma unroll
                for (int j = 0; j < 8; ++j) acc[r][j] = fmaf(av, bv[j], acc[r][j]);
            }
        }
    }
}

// ---- K1: pre = nf @ bcat via bf16 MFMA; one wave = 16 nodes x 640 cols ----
__global__ __launch_bounds__(256) void k_node_pre(const float* __restrict__ nf,
                                                  const u16* __restrict__ bcf,
                                                  u16* __restrict__ pre16,
                                                  u16* __restrict__ premsg16) {
    int t = threadIdx.x, w = t >> 6, l = t & 63;
    int n0 = blockIdx.x * 64 + w * 16;
    int rsel = l & 15, kb = l >> 4;
    int nA = n0 + rsel;
    size_t nAc = (nA < 25000) ? (size_t)nA : 24999;   // garbage only feeds unstored C rows
    const float* ap = &nf[nAc * 128 + kb * 8];
    bf8 a[4];
#pragma unroll
    for (int s = 0; s < 4; ++s) {
        float4 x = *(const float4*)&ap[s * 32];
        float4 y = *(const float4*)&ap[s * 32 + 4];
        a[s] = pack8(x, y);
    }
    int nC = n0 + kb * 4;
#pragma unroll 4
    for (int cb = 0; cb < 40; ++cb) {
        f4 acc = {0.f, 0.f, 0.f, 0.f};
#pragma unroll
        for (int s = 0; s < 4; ++s) {
            bf8 b = *(const bf8*)&bcf[(size_t)((cb * 4 + s) * 64 + l) * 8];
            acc = __builtin_amdgcn_mfma_f32_16x16x32_bf16(a[s], b, acc, 0, 0, 0);
        }
#pragma unroll
        for (int r = 0; r < 4; ++r) {
            int nn = nC + r;
            if (nn < 25000) {
                if (cb < 32) pre16[(size_t)nn * 512 + cb * 16 + rsel] = f2b(acc[r]);
                else premsg16[(size_t)nn * 128 + (cb - 32) * 16 + rsel] = f2b(acc[r]);
            }
        }
    }
}

// ---- K2a: histogram of dst ----
__global__ void k_hist(const int* __restrict__ eidx, int* __restrict__ count) {
    int e = blockIdx.x * 256 + threadIdx.x;
    if (e < 400000) atomicAdd(&count[eidx[e]], 1);
}

// ---- K2b: exclusive scan (single block) count -> cursor ----
__global__ __launch_bounds__(1024) void k_scan(const int* __restrict__ count,
                                               int* __restrict__ cursor) {
    __shared__ int sums[1024];
    int t = threadIdx.x;
    int base = t * 25;
    int v[25];
    int local = 0;
#pragma unroll
    for (int i = 0; i < 25; ++i) {
        int idx = base + i;
        int c = (idx < 25000) ? count[idx] : 0;
        v[i] = local;
        local += c;
    }
    sums[t] = local;
    __syncthreads();
    for (int off = 1; off < 1024; off <<= 1) {
        int x = (t >= off) ? sums[t - off] : 0;
        __syncthreads();
        sums[t] += x;
        __syncthreads();
    }
    int prefix = (t == 0) ? 0 : sums[t - 1];
#pragma unroll
    for (int i = 0; i < 25; ++i) {
        int idx = base + i;
        if (idx < 25000) cursor[idx] = prefix + v[i];
    }
}

// ---- K2c: scatter edge ids + dst/src into dst-sorted order ----
__global__ void k_scatter(const int* __restrict__ eidx, int* __restrict__ cursor,
                          int* __restrict__ perm, int* __restrict__ dsts,
                          int* __restrict__ srcs) {
    int e = blockIdx.x * 256 + threadIdx.x;
    if (e < 400000) {
        int d = eidx[e];
        int p = atomicAdd(&cursor[d], 1);
        perm[p] = e;
        dsts[p] = d;
        srcs[p] = eidx[400000 + e];
    }
}

// ---- K3: edge logits via bf16 MFMA over dst-sorted edges + atomic max (R4-proven) ----
__global__ __launch_bounds__(256) void k_edge_logits(
        const float* __restrict__ ef, const int* __restrict__ perm,
        const int* __restrict__ dsts, const int* __restrict__ srcs,
        const u16* __restrict__ ewfrag, const u16* __restrict__ pre16,
        const float* __restrict__ btot, const float* __restrict__ aproj,
        float* __restrict__ logits_s, unsigned* __restrict__ maxkey) {
    __shared__ int eperm[64], dstl[64], srcl[64];
    int t = threadIdx.x;
    int w = t >> 6, l = t & 63;
    int p0 = blockIdx.x * 64;
    int row = l & 15, kb = l >> 4;

    if (t < 64) {
        eperm[t] = perm[p0 + t];
        dstl[t] = dsts[p0 + t];
        srcl[t] = srcs[p0 + t];
    }
    __syncthreads();

    int ea = eperm[w * 16 + row];
    const float* ap = &ef[(size_t)ea * 64 + kb * 8];
    float4 a00 = *(const float4*)ap;
    float4 a01 = *(const float4*)(ap + 4);
    float4 a10 = *(const float4*)(ap + 32);
    float4 a11 = *(const float4*)(ap + 36);
    bf8 a0 = pack8(a00, a01), a1 = pack8(a10, a11);

    int ed[4], es[4];
#pragma unroll
    for (int r = 0; r < 4; ++r) {
        int i4 = w * 16 + kb * 4 + r;
        ed[r] = dstl[i4];
        es[r] = srcl[i4];
    }

    float part0[4] = {0.f, 0.f, 0.f, 0.f}, part1[4] = {0.f, 0.f, 0.f, 0.f};
#pragma unroll
    for (int c = 0; c < 16; ++c) {
        bf8 b0 = *(const bf8*)&ewfrag[(size_t)((c * 2 + 0) * 64 + l) * 8];
        bf8 b1 = *(const bf8*)&ewfrag[(size_t)((c * 2 + 1) * 64 + l) * 8];
        f4 acc = {0.f, 0.f, 0.f, 0.f};
        acc = __builtin_amdgcn_mfma_f32_16x16x32_bf16(a0, b0, acc, 0, 0, 0);
        acc = __builtin_amdgcn_mfma_f32_16x16x32_bf16(a1, b1, acc, 0, 0, 0);
        int col = c * 16 + row;
        float bt = btot[col], apj = aproj[col];
#pragma unroll
        for (int r = 0; r < 4; ++r) {
            float pi = b2f(pre16[(size_t)ed[r] * 512 + col]);
            float pj = b2f(pre16[(size_t)es[r] * 512 + 256 + col]);
            float hid = acc[r] + pi + pj + bt;
            hid = hid >= 0.f ? hid : NEG * hid;
            if (c < 8) part0[r] = fmaf(hid, apj, part0[r]);
            else       part1[r] = fmaf(hid, apj, part1[r]);
        }
    }
#pragma unroll
    for (int m = 1; m < 16; m <<= 1) {
#pragma unroll
        for (int r = 0; r < 4; ++r) {
            part0[r] += __shfl_xor(part0[r], m);
            part1[r] += __shfl_xor(part1[r], m);
        }
    }
    if (row == 0) {
#pragma unroll
        for (int r = 0; r < 4; ++r) {
            int p = p0 + w * 16 + kb * 4 + r;
            logits_s[(size_t)p * 2 + 0] = part0[r];
            logits_s[(size_t)p * 2 + 1] = part1[r];
            atomicMax(&maxkey[ed[r] * 2 + 0], fkey(part0[r]));
            atomicMax(&maxkey[ed[r] * 2 + 1], fkey(part1[r]));
        }
    }
}

// ---- K4: ex = exp(logit - max); denom += ex  (sorted space) ----
__global__ void k_soft(const int* __restrict__ dsts, float* __restrict__ logits_s,
                       const unsigned* __restrict__ maxkey, float* __restrict__ denom) {
    int idx = blockIdx.x * 256 + threadIdx.x;
    if (idx >= 800000) return;
    int p = idx >> 1, h = idx & 1;
    int d = dsts[p];
    float m = keyf(maxkey[d * 2 + h]);
    float ex = __expf(logits_s[idx] - m);
    logits_s[idx] = ex;
    atomicAdd(&denom[d * 2 + h], ex);
}

// ---- K5: messages via bf16 MFMA (R4-proven) + bf16 premsg gather + seg reduce ----
__global__ __launch_bounds__(256) void k_messages(
        const float* __restrict__ ef, const int* __restrict__ perm,
        const int* __restrict__ dsts, const int* __restrict__ srcs,
        const u16* __restrict__ msgfrag, const u16* __restrict__ premsg16,
        const float* __restrict__ exs, const float* __restrict__ denom,
        float* __restrict__ agg) {
    __shared__ float Msg[64 * 132];
    __shared__ int dstl[64], srcl[64], eperm[64];
    __shared__ float attl[64][2];
    int t = threadIdx.x;
    int w = t >> 6, l = t & 63;
    int p0 = blockIdx.x * 64;
    int row = l & 15, kb = l >> 4;

    if (t < 64) {
        int p = p0 + t;
        eperm[t] = perm[p];
        int d = dsts[p];
        dstl[t] = d;
        srcl[t] = srcs[p];
        attl[t][0] = exs[(size_t)p * 2 + 0] / denom[d * 2 + 0];
        attl[t][1] = exs[(size_t)p * 2 + 1] / denom[d * 2 + 1];
    }
    __syncthreads();

    int ea = eperm[w * 16 + row];
    const float* apr = &ef[(size_t)ea * 64 + kb * 8];
    float4 a00 = *(const float4*)apr;
    float4 a01 = *(const float4*)(apr + 4);
    float4 a10 = *(const float4*)(apr + 32);
    float4 a11 = *(const float4*)(apr + 36);
    bf8 a0 = pack8(a00, a01), a1 = pack8(a10, a11);

    int esr[4];
    float at0[4], at1[4];
#pragma unroll
    for (int r = 0; r < 4; ++r) {
        int i4 = w * 16 + kb * 4 + r;
        esr[r] = srcl[i4];
        at0[r] = attl[i4][0];
        at1[r] = attl[i4][1];
    }

#pragma unroll
    for (int c = 0; c < 8; ++c) {
        bf8 b0 = *(const bf8*)&msgfrag[(size_t)((c * 2 + 0) * 64 + l) * 8];
        bf8 b1 = *(const bf8*)&msgfrag[(size_t)((c * 2 + 1) * 64 + l) * 8];
        f4 acc = {0.f, 0.f, 0.f, 0.f};
        acc = __builtin_amdgcn_mfma_f32_16x16x32_bf16(a0, b0, acc, 0, 0, 0);
        acc = __builtin_amdgcn_mfma_f32_16x16x32_bf16(a1, b1, acc, 0, 0, 0);
        int col = c * 16 + row;             // msg col 0..127; head = c>>2
#pragma unroll
        for (int r = 0; r < 4; ++r) {
            float m = acc[r] + b2f(premsg16[(size_t)esr[r] * 128 + col]);
            float wm = ((c < 4) ? at0[r] : at1[r]) * m;
            Msg[(w * 16 + kb * 4 + r) * 132 + col] = wm;
        }
    }
    __syncthreads();

    // segmented reduction over sorted dst; one atomic per (run, col)
    int c = t & 127, half = t >> 7;
    int r0 = half * 32, r1 = r0 + 32;
    int cur = dstl[r0];
    float sum = 0.f;
    for (int r = r0; r < r1; ++r) {
        int d = dstl[r];
        if (d != cur) {
            atomicAdd(&agg[(size_t)cur * 128 + c], sum);
            sum = 0.f;
            cur = d;
        }
        sum += Msg[r * 132 + c];
    }
    atomicAdd(&agg[(size_t)cur * 128 + c], sum);
}

// ---- K6: out = (agg + msg_b*[deg>0]) @ out_W + out_b ----
__global__ __launch_bounds__(256) void k_out(
        const float* __restrict__ agg, const int* __restrict__ count,
        const float* __restrict__ msgb, const float* __restrict__ outW,
        const float* __restrict__ outb, float* __restrict__ out) {
    __shared__ float Al[64 * 128];
    __shared__ float Bl[64 * 128];
    int t = threadIdx.x, n0 = blockIdx.x * 64;
    int trow = t >> 4, tcol = t & 15;
#pragma unroll
    for (int q = 0; q < 8; ++q) {
        int g = t + 256 * q;
        int i = g >> 5, k4 = (g & 31) * 4;
        int n = n0 + i;
        float4 v = make_float4(0.f, 0.f, 0.f, 0.f);
        if (n < 25000) {
            v = *(const float4*)&agg[(size_t)n * 128 + k4];
            if (count[n] > 0) {
                float4 mb = *(const float4*)&msgb[k4];
                v.x += mb.x; v.y += mb.y; v.z += mb.z; v.w += mb.w;
            }
        }
        *(float4*)&Al[i * 128 + k4] = v;
    }
    float acc[4][8] = {};
    for (int kh = 0; kh < 2; ++kh) {
        __syncthreads();
#pragma unroll
        for (int q = 0; q < 8; ++q) {
            int g = t + 256 * q;
            int k = g >> 5, c4 = (g & 31) * 4;
            *(float4*)&Bl[k * 128 + c4] = *(const float4*)&outW[(kh * 64 + k) * 128 + c4];
        }
        __syncthreads();
        gemm_tile(Al, 128, kh * 64, Bl, trow, tcol, acc);
    }
    float ob[8];
    *(float4*)ob = *(const float4*)&outb[tcol * 8];
    *(float4*)(ob + 4) = *(const float4*)&outb[tcol * 8 + 4];
#pragma unroll
    for (int r = 0; r < 4; ++r) {
        int n = n0 + trow * 4 + r;
        if (n < 25000) {
            *(float4*)&out[(size_t)n * 128 + tcol * 8] =
                make_float4(acc[r][0] + ob[0], acc[r][1] + ob[1], acc[r][2] + ob[2], acc[r][3] + ob[3]);
            *(float4*)&out[(size_t)n * 128 + tcol * 8 + 4] =
                make_float4(acc[r][4] + ob[4], acc[r][5] + ob[5], acc[r][6] + ob[6], acc[r][7] + ob[7]);
        }
    }
}

extern "C" void kernel_launch(void* const* d_in, const int* in_sizes, int n_in,
                              void* d_out, int out_size, void* d_ws, size_t ws_size,
                              hipStream_t stream) {
    const float* nf    = (const float*)d_in[0];
    const float* ef    = (const float*)d_in[1];
    const int*   eidx  = (const int*)d_in[2];
    const float* niW   = (const float*)d_in[3];
    const float* nib   = (const float*)d_in[4];
    const float* njW   = (const float*)d_in[5];
    const float* njb   = (const float*)d_in[6];
    const float* eW    = (const float*)d_in[7];
    const float* eb    = (const float*)d_in[8];
    const float* aproj = (const float*)d_in[9];
    const float* msgW  = (const float*)d_in[10];
    const float* msgb  = (const float*)d_in[11];
    const float* outW  = (const float*)d_in[12];
    const float* outb  = (const float*)d_in[13];

    float* ws = (float*)d_ws;
    u16*   pre16     = (u16*)(ws + OFF_P16);
    u16*   premsg16  = (u16*)(ws + OFF_PM16);
    u16*   bcf       = (u16*)(ws + OFF_BCF);
    float* btot      = ws + OFF_BTOT;
    float* logits_s  = ws + OFF_LOG;
    unsigned* maxkey = (unsigned*)(ws + OFF_MAX);
    float* denom     = ws + OFF_DEN;
    float* agg       = ws + OFF_AGG;
    int*   count     = (int*)(ws + OFF_CNT);
    int*   cursor    = (int*)(ws + OFF_CUR);
    int*   perm      = (int*)(ws + OFF_PERM);
    int*   dsts      = (int*)(ws + OFF_DST);
    int*   srcs      = (int*)(ws + OFF_SRC);
    u16*   ewfrag    = (u16*)(ws + OFF_EWF);
    u16*   msgfrag   = (u16*)(ws + OFF_MWF);

    // zero maxkey + denom + agg + count (contiguous)
    hipMemsetAsync(ws + OFF_MAX, 0, (size_t)(SZ_MAX + SZ_DEN + SZ_AGG + SZ_CNT) * 4, stream);

    k_prep<<<320, 256, 0, stream>>>(niW, njW, msgW, eW, nib, njb, eb,
                                    bcf, btot, ewfrag, msgfrag);
    k_node_pre<<<391, 256, 0, stream>>>(nf, bcf, pre16, premsg16);
    k_hist<<<1563, 256, 0, stream>>>(eidx, count);
    k_scan<<<1, 1024, 0, stream>>>(count, cursor);
    k_scatter<<<1563, 256, 0, stream>>>(eidx, cursor, perm, dsts, srcs);
    k_edge_logits<<<6250, 256, 0, stream>>>(ef, perm, dsts, srcs, ewfrag, pre16,
                                            btot, aproj, logits_s, maxkey);
    k_soft<<<3125, 256, 0, stream>>>(dsts, logits_s, maxkey, denom);
    k_messages<<<6250, 256, 0, stream>>>(ef, perm, dsts, srcs, msgfrag, premsg16,
                                         logits_s, denom, agg);
    k_out<<<391, 256, 0, stream>>>(agg, count, msgb, outW, outb, (float*)d_out);
}